// Round 5
// baseline (1312.334 us; speedup 1.0000x reference)
//
#include <hip/hip_runtime.h>

typedef unsigned short u16;
typedef __bf16 bf16x8 __attribute__((ext_vector_type(8)));
typedef float f32x4 __attribute__((ext_vector_type(4)));

#define DEV static __device__ __forceinline__

DEV u16 f2bf(float f) {
    unsigned int u = __builtin_bit_cast(unsigned int, f);
    u += 0x7FFFu + ((u >> 16) & 1u);
    return (u16)(u >> 16);
}

DEV bf16x8 frag_ld(const u16* p) {  // p must be 16B aligned
    return __builtin_bit_cast(bf16x8, *(const uint4*)p);
}

DEV float sigm(float x) { return 1.f / (1.f + __expf(-x)); }

// ---------------- tiny setup kernels ----------------
__global__ void kInit(const float* __restrict__ noise, const float* __restrict__ mean,
                      const float* __restrict__ logv, float* __restrict__ slots) {
    int id = blockIdx.x * 256 + threadIdx.x;            // 0..131071
    int d = id & 255;
    slots[id] = mean[d] + __expf(logv[d]) * noise[id];
}

// generic 32x32-tiled transpose: out[C][R] = in[R][C]; grid (C/32, R/32), 256 thr
__global__ void kT(const float* __restrict__ in, float* __restrict__ out, int R, int C) {
    __shared__ float tile[32][33];
    const int tx = threadIdx.x & 31, ty = threadIdx.x >> 5;  // ty 0..7
    const int c0 = blockIdx.x * 32, r0 = blockIdx.y * 32;
    #pragma unroll
    for (int i = 0; i < 4; ++i)
        tile[ty + i * 8][tx] = in[(size_t)(r0 + ty + i * 8) * C + c0 + tx];
    __syncthreads();
    #pragma unroll
    for (int i = 0; i < 4; ++i)
        out[(size_t)(c0 + ty + i * 8) * R + r0 + tx] = tile[tx][ty + i * 8];
}

// ---------------- kLN: LayerNorm(inputs) -> xln bf16 [B*N][256] ----------------
// grid 65536 blocks (4 rows each, one wave per row), 256 threads
__global__ __launch_bounds__(256) void kLN(
    const float* __restrict__ X, const float* __restrict__ gin, const float* __restrict__ bin,
    u16* __restrict__ xln)
{
    const int w = threadIdx.x >> 6, lane = threadIdx.x & 63;
    const size_t row = (size_t)blockIdx.x * 4 + w;
    const int c = lane << 2;
    const float4 x = *(const float4*)(X + row * 256 + c);
    float s1 = x.x + x.y + x.z + x.w;
    float s2 = x.x * x.x + x.y * x.y + x.z * x.z + x.w * x.w;
    #pragma unroll
    for (int o = 32; o > 0; o >>= 1) { s1 += __shfl_xor(s1, o); s2 += __shfl_xor(s2, o); }
    const float mu = s1 * (1.f / 256.f);
    const float rs = rsqrtf(s2 * (1.f / 256.f) - mu * mu + 1e-5f);
    const float4 g4 = *(const float4*)(gin + c);
    const float4 b4 = *(const float4*)(bin + c);
    ushort4 pk;
    pk.x = f2bf((x.x - mu) * rs * g4.x + b4.x);
    pk.y = f2bf((x.y - mu) * rs * g4.y + b4.y);
    pk.z = f2bf((x.z - mu) * rs * g4.z + b4.z);
    pk.w = f2bf((x.w - mu) * rs * g4.w + b4.w);
    *(ushort4*)(xln + row * 256 + c) = pk;
}

// ---------------- kB1: LN(slots) -> q -> q2 = SCALE*q@Wk (bf16), c = SCALE*q.bk ------
// grid 64 (one b each), 256 threads
__global__ __launch_bounds__(256) void kB1(
    const float* __restrict__ slots, const float* __restrict__ gs, const float* __restrict__ bs,
    const float* __restrict__ WqT, const float* __restrict__ bq,
    const float* __restrict__ Wk, const float* __restrict__ bk,
    u16* __restrict__ q2o, float* __restrict__ co)
{
    __shared__ float SN[8][256];
    __shared__ float Qf[8][256];
    __shared__ float redc[4][8];
    const int t = threadIdx.x, b = blockIdx.x;
    const int w = t >> 6, lane = t & 63;
    // LN: wave w normalizes rows 2w, 2w+1
    #pragma unroll
    for (int rr = 0; rr < 2; ++rr) {
        const int r = w * 2 + rr;
        const int c = lane * 4;
        const float4 x = *(const float4*)(slots + ((size_t)b * 8 + r) * 256 + c);
        float s1 = x.x + x.y + x.z + x.w;
        float s2 = x.x * x.x + x.y * x.y + x.z * x.z + x.w * x.w;
        #pragma unroll
        for (int o = 32; o > 0; o >>= 1) { s1 += __shfl_xor(s1, o); s2 += __shfl_xor(s2, o); }
        const float mu = s1 * (1.f / 256.f);
        const float rs = rsqrtf(s2 * (1.f / 256.f) - mu * mu + 1e-5f);
        const float4 g4 = *(const float4*)(gs + c);
        const float4 b4 = *(const float4*)(bs + c);
        SN[r][c + 0] = (x.x - mu) * rs * g4.x + b4.x;
        SN[r][c + 1] = (x.y - mu) * rs * g4.y + b4.y;
        SN[r][c + 2] = (x.z - mu) * rs * g4.z + b4.z;
        SN[r][c + 3] = (x.w - mu) * rs * g4.w + b4.w;
    }
    __syncthreads();
    // q[i][t] = SN[i] . WqT[:,t] + bq[t]
    float qv[8] = {};
    #pragma unroll 2
    for (int d = 0; d < 256; ++d) {
        const float wq = WqT[(size_t)d * 256 + t];
        #pragma unroll
        for (int i = 0; i < 8; ++i) qv[i] += wq * SN[i][d];
    }
    const float bqt = bq[t], bkt = bk[t];
    #pragma unroll
    for (int i = 0; i < 8; ++i) { qv[i] += bqt; Qf[i][t] = qv[i]; }
    // c[i] = SCALE * sum_t q[i][t]*bk[t]
    #pragma unroll
    for (int i = 0; i < 8; ++i) {
        float v = qv[i] * bkt;
        #pragma unroll
        for (int o = 32; o > 0; o >>= 1) v += __shfl_xor(v, o);
        if (lane == 0) redc[w][i] = v;
    }
    __syncthreads();
    if (t < 8) co[b * 8 + t] = (redc[0][t] + redc[1][t] + redc[2][t] + redc[3][t]) * 0.0625f;
    // q2[i][t] = SCALE * sum_e q[i][e] * Wk[e][t]
    float av[8] = {};
    #pragma unroll 2
    for (int e = 0; e < 256; ++e) {
        const float wk = Wk[(size_t)e * 256 + t];
        #pragma unroll
        for (int i = 0; i < 8; ++i) av[i] += wk * Qf[i][e];
    }
    #pragma unroll
    for (int i = 0; i < 8; ++i)
        q2o[((size_t)b * 16 + i) * 256 + t] = f2bf(av[i] * 0.0625f);
}

// ---------------- kB2: per (64-n tile, b): dots -> softmax -> attn, u2 = attn@xln -----
// grid (64 ntiles, 64 b), 256 threads (4 waves), ~75 KB LDS -> 2 blocks/CU
__global__ __launch_bounds__(256) void kB2(
    const u16* __restrict__ q2, const float* __restrict__ co, const u16* __restrict__ xln,
    float* __restrict__ attn_out, float* __restrict__ part, float* __restrict__ asum_part,
    int write_attn)
{
    __shared__ u16 Xr[64 * 264];      // xln tile, row layout (n-major), pad 8
    __shared__ u16 Xt[256 * 72];      // transposed (e-major), pad 8
    __shared__ float dsc[8 * 68];
    __shared__ u16 attL[16 * 72];     // rows 8..15 uninit (feed unread MFMA D rows)
    const int tid = threadIdx.x;
    const int w = tid >> 6, lane = tid & 63;
    const int quad = lane >> 4, l16 = lane & 15;
    const int b = blockIdx.y, nt = blockIdx.x;
    const int n0 = nt << 6;

    // stage xln tile (32 KB)
    const u16* xsrc = xln + ((size_t)b * 4096 + n0) * 256;
    #pragma unroll
    for (int it = 0; it < 8; ++it) {
        const int chunk = tid + it * 256;
        const int r = chunk >> 5, cc = (chunk & 31) << 3;
        *(uint4*)(Xr + r * 264 + cc) = *(const uint4*)(xsrc + (size_t)r * 256 + cc);
    }
    __syncthreads();

    // dots: D[i][n] = sum_e q2[i][e] * xln[n][e]; wave w covers n = w*16..+15
    f32x4 acc = {0.f, 0.f, 0.f, 0.f};
    const u16* qb = q2 + (size_t)b * 16 * 256;
    #pragma unroll
    for (int k0 = 0; k0 < 256; k0 += 32) {
        const bf16x8 a = frag_ld(qb + l16 * 256 + k0 + quad * 8);
        const bf16x8 bb = frag_ld(Xr + (w * 16 + l16) * 264 + k0 + quad * 8);
        acc = __builtin_amdgcn_mfma_f32_16x16x32_bf16(a, bb, acc, 0, 0, 0);
    }
    // transpose Xr -> Xt (thread = column e)
    #pragma unroll
    for (int g = 0; g < 8; ++g) {
        uint4 pk;
        pk.x = (unsigned)Xr[(g * 8 + 0) * 264 + tid] | ((unsigned)Xr[(g * 8 + 1) * 264 + tid] << 16);
        pk.y = (unsigned)Xr[(g * 8 + 2) * 264 + tid] | ((unsigned)Xr[(g * 8 + 3) * 264 + tid] << 16);
        pk.z = (unsigned)Xr[(g * 8 + 4) * 264 + tid] | ((unsigned)Xr[(g * 8 + 5) * 264 + tid] << 16);
        pk.w = (unsigned)Xr[(g * 8 + 6) * 264 + tid] | ((unsigned)Xr[(g * 8 + 7) * 264 + tid] << 16);
        *(uint4*)(Xt + tid * 72 + g * 8) = pk;
    }
    if (quad < 2) {
        #pragma unroll
        for (int rg = 0; rg < 4; ++rg)
            dsc[(quad * 4 + rg) * 68 + w * 16 + l16] = acc[rg];
    }
    __syncthreads();

    if (tid < 64) {                   // softmax over 8 slots for column j (wave 0)
        const int j = tid;
        float v0[8], mx = -1e30f;
        #pragma unroll
        for (int i = 0; i < 8; ++i) { v0[i] = dsc[i * 68 + j] + co[b * 8 + i]; mx = fmaxf(mx, v0[i]); }
        float sum = 0.f;
        #pragma unroll
        for (int i = 0; i < 8; ++i) { v0[i] = __expf(v0[i] - mx); sum += v0[i]; }
        const float inv = 1.f / sum;
        #pragma unroll
        for (int i = 0; i < 8; ++i) {
            const float a = v0[i] * inv + 1e-8f;
            v0[i] = a;
            attL[i * 72 + j] = f2bf(a);
            if (write_attn) attn_out[((size_t)b * 8 + i) * 4096 + n0 + j] = a;
        }
        #pragma unroll
        for (int i = 0; i < 8; ++i) {   // asum[i] = sum_n attn[i][n] over this tile
            float v = v0[i];
            #pragma unroll
            for (int o = 32; o > 0; o >>= 1) v += __shfl_xor(v, o);
            if (tid == 0) asum_part[nt * 512 + b * 8 + i] = v;
        }
    }
    __syncthreads();

    // u2: D[i][e] = sum_n attn[i][n] * xln[n][e]; wave w covers e = w*64..+63
    f32x4 ua[4] = {};
    #pragma unroll
    for (int k0 = 0; k0 < 64; k0 += 32) {
        const bf16x8 a = frag_ld(attL + l16 * 72 + k0 + quad * 8);
        #pragma unroll
        for (int n2 = 0; n2 < 4; ++n2) {
            const bf16x8 bb = frag_ld(Xt + (w * 64 + n2 * 16 + l16) * 72 + k0 + quad * 8);
            ua[n2] = __builtin_amdgcn_mfma_f32_16x16x32_bf16(a, bb, ua[n2], 0, 0, 0);
        }
    }
    float* up = part + ((size_t)nt * 64 + b) * 2048;    // [64 nt][64 b][8][256]
    if (quad < 2) {
        #pragma unroll
        for (int n2 = 0; n2 < 4; ++n2)
            #pragma unroll
            for (int rg = 0; rg < 4; ++rg)
                up[(quad * 4 + rg) * 256 + w * 64 + n2 * 16 + l16] = ua[n2][rg];
    }
}

// reduce 64 n-tile partials -> u2g [64*8*256], asumg [64*8]
__global__ __launch_bounds__(256) void kB2r(
    const float* __restrict__ part, const float* __restrict__ asum_part,
    float* __restrict__ u2g, float* __restrict__ asumg)
{
    const int id = blockIdx.x * 256 + threadIdx.x;     // 0..131071
    float s = 0.f;
    #pragma unroll 8
    for (int i = 0; i < 64; ++i) s += part[(size_t)i * 131072 + id];
    u2g[id] = s;
    if (blockIdx.x == 0) {
        for (int k = threadIdx.x; k < 512; k += 256) {
            float s2 = 0.f;
            #pragma unroll 8
            for (int i = 0; i < 64; ++i) s2 += asum_part[i * 512 + k];
            asumg[k] = s2;
        }
    }
}

// ---------------- kB3: updates = u2@WvT + bv*asum, GRU + LN + MLP (4 rows/block) -----
__global__ __launch_bounds__(256) void kB3(
    const float* __restrict__ u2g, const float* __restrict__ asumg,
    const float* __restrict__ sl_in,
    const float* __restrict__ WvT, const float* __restrict__ bv,
    const float* __restrict__ WihT, const float* __restrict__ bih,
    const float* __restrict__ WhhT, const float* __restrict__ bhh,
    const float* __restrict__ W1T, const float* __restrict__ b1,
    const float* __restrict__ W2T, const float* __restrict__ b2,
    const float* __restrict__ gf, const float* __restrict__ bff,
    float* __restrict__ sl_out)
{
    __shared__ float U2[4][256], U[4][256], S[4][256], SN[4][256], Xs[4][256];
    const int t = threadIdx.x;
    const int w = t >> 6, lane = t & 63;
    const size_t row0 = (size_t)blockIdx.x * 4;

    #pragma unroll
    for (int r = 0; r < 4; ++r) {
        U2[r][t] = u2g[(row0 + r) * 256 + t];
        S[r][t] = sl_in[(row0 + r) * 256 + t];
    }
    __syncthreads();
    // updates row r, col t = sum_e u2[r][e]*Wv[t][e] + bv[t]*asum[r]
    float uv[4] = {};
    #pragma unroll 2
    for (int e = 0; e < 256; ++e) {
        const float wv = WvT[(size_t)e * 256 + t];
        #pragma unroll
        for (int r = 0; r < 4; ++r) uv[r] += wv * U2[r][e];
    }
    const float bvt = bv[t];
    #pragma unroll
    for (int r = 0; r < 4; ++r) U[r][t] = uv[r] + bvt * asumg[row0 + r];
    __syncthreads();

    float ir[4] = {}, iz[4] = {}, in_[4] = {}, hr[4] = {}, hz[4] = {}, hn[4] = {};
    #pragma unroll 2
    for (int d = 0; d < 256; ++d) {
        const float wa = WihT[(size_t)d * 768 + t];
        const float wb = WihT[(size_t)d * 768 + 256 + t];
        const float wc = WihT[(size_t)d * 768 + 512 + t];
        const float we = WhhT[(size_t)d * 768 + t];
        const float wf = WhhT[(size_t)d * 768 + 256 + t];
        const float wg = WhhT[(size_t)d * 768 + 512 + t];
        #pragma unroll
        for (int r = 0; r < 4; ++r) {
            const float uvd = U[r][d], sv = S[r][d];
            ir[r] += wa * uvd;  iz[r] += wb * uvd;  in_[r] += wc * uvd;
            hr[r] += we * sv;   hz[r] += wf * sv;   hn[r] += wg * sv;
        }
    }
    const float b_ir = bih[t], b_iz = bih[256 + t], b_in = bih[512 + t];
    const float b_hr = bhh[t], b_hz = bhh[256 + t], b_hn = bhh[512 + t];
    float hnew[4];
    #pragma unroll
    for (int r = 0; r < 4; ++r) {
        const float rg = sigm(ir[r] + b_ir + hr[r] + b_hr);
        const float zg = sigm(iz[r] + b_iz + hz[r] + b_hz);
        const float ng = tanhf(in_[r] + b_in + rg * (hn[r] + b_hn));
        hnew[r] = (1.f - zg) * ng + zg * S[r][t];
    }
    __syncthreads();                       // done reading U
    #pragma unroll
    for (int r = 0; r < 4; ++r) U[r][t] = hnew[r];   // reuse U as Hn
    __syncthreads();
    // wave w normalizes row w
    {
        const int c = lane * 4;
        const float4 x = *(const float4*)&U[w][c];
        float s1 = x.x + x.y + x.z + x.w;
        float s2 = x.x * x.x + x.y * x.y + x.z * x.z + x.w * x.w;
        #pragma unroll
        for (int o = 32; o > 0; o >>= 1) { s1 += __shfl_xor(s1, o); s2 += __shfl_xor(s2, o); }
        const float mu = s1 * (1.f / 256.f);
        const float rs = rsqrtf(s2 * (1.f / 256.f) - mu * mu + 1e-5f);
        const float4 g4 = *(const float4*)(gf + c);
        const float4 b4 = *(const float4*)(bff + c);
        SN[w][c + 0] = (x.x - mu) * rs * g4.x + b4.x;
        SN[w][c + 1] = (x.y - mu) * rs * g4.y + b4.y;
        SN[w][c + 2] = (x.z - mu) * rs * g4.z + b4.z;
        SN[w][c + 3] = (x.w - mu) * rs * g4.w + b4.w;
    }
    __syncthreads();
    float hacc[4] = {};
    #pragma unroll 4
    for (int d = 0; d < 256; ++d) {
        const float w1 = W1T[(size_t)d * 256 + t];
        #pragma unroll
        for (int r = 0; r < 4; ++r) hacc[r] += w1 * SN[r][d];
    }
    const float bb1 = b1[t];
    #pragma unroll
    for (int r = 0; r < 4; ++r) Xs[r][t] = fmaxf(hacc[r] + bb1, 0.f);
    __syncthreads();
    float oacc[4] = {};
    #pragma unroll 4
    for (int j = 0; j < 256; ++j) {
        const float w2 = W2T[(size_t)j * 256 + t];
        #pragma unroll
        for (int r = 0; r < 4; ++r) oacc[r] += w2 * Xs[r][j];
    }
    const float bb2 = b2[t];
    #pragma unroll
    for (int r = 0; r < 4; ++r)
        sl_out[(row0 + r) * 256 + t] = hnew[r] + oacc[r] + bb2;
}

// ---------------- launch ----------------
extern "C" void kernel_launch(void* const* d_in, const int* in_sizes, int n_in,
                              void* d_out, int out_size, void* d_ws, size_t ws_size,
                              hipStream_t stream) {
    const float* inputs = (const float*)d_in[0];
    const float* noise  = (const float*)d_in[1];
    const float* smean  = (const float*)d_in[2];
    const float* slogv  = (const float*)d_in[3];
    const float* Wq  = (const float*)d_in[4];
    const float* bq  = (const float*)d_in[5];
    const float* Wk  = (const float*)d_in[6];
    const float* bk  = (const float*)d_in[7];
    const float* Wv  = (const float*)d_in[8];
    const float* bv  = (const float*)d_in[9];
    const float* Wih = (const float*)d_in[10];
    const float* bih = (const float*)d_in[11];
    const float* Whh = (const float*)d_in[12];
    const float* bhh = (const float*)d_in[13];
    const float* W1  = (const float*)d_in[14];
    const float* b1  = (const float*)d_in[15];
    const float* W2  = (const float*)d_in[16];
    const float* b2  = (const float*)d_in[17];
    const float* gin = (const float*)d_in[18];
    const float* bin = (const float*)d_in[19];
    const float* gs  = (const float*)d_in[20];
    const float* bs  = (const float*)d_in[21];
    const float* gf  = (const float*)d_in[22];
    const float* bff = (const float*)d_in[23];

    // workspace layout (~172.1 MB)
    char* ws = (char*)d_ws;
    u16*   xlnw  = (u16*)(ws);                          // 134,217,728 B  [B*N][256] bf16
    u16*   q2w   = (u16*)(ws + 134217728ull);           //     524,288 B  [B][16][256] bf16
    float* cw    = (float*)(ws + 134742016ull);         //       2,048 B  [B][8]
    float* slots = (float*)(ws + 134744064ull);         //     524,288 B
    float* u2g   = (float*)(ws + 135268352ull);         //     524,288 B  [B][8][256]
    float* asumg = (float*)(ws + 135792640ull);         //       2,048 B  [B][8]
    float* WqT   = (float*)(ws + 135794688ull);         //     262,144 B
    float* WvT   = (float*)(ws + 136056832ull);         //     262,144 B
    float* WihT  = (float*)(ws + 136318976ull);         //     786,432 B
    float* WhhT  = (float*)(ws + 137105408ull);         //     786,432 B
    float* W1T   = (float*)(ws + 137891840ull);         //     262,144 B
    float* W2T   = (float*)(ws + 138153984ull);         //     262,144 B
    float* partw = (float*)(ws + 138416128ull);         //  33,554,432 B  [64][64][8][256]
    float* aspw  = (float*)(ws + 171970560ull);         //     131,072 B  [64][512]

    float* out = (float*)d_out;
    float* attn_out = out + 131072;                     // [B,S,N] after slots [B,S,D]

    kInit<<<512, 256, 0, stream>>>(noise, smean, slogv, slots);
    kT<<<dim3(8, 8),  256, 0, stream>>>(Wq,  WqT,  256, 256);
    kT<<<dim3(8, 8),  256, 0, stream>>>(Wv,  WvT,  256, 256);
    kT<<<dim3(8, 24), 256, 0, stream>>>(Wih, WihT, 768, 256);
    kT<<<dim3(8, 24), 256, 0, stream>>>(Whh, WhhT, 768, 256);
    kT<<<dim3(8, 8),  256, 0, stream>>>(W1,  W1T,  256, 256);
    kT<<<dim3(8, 8),  256, 0, stream>>>(W2,  W2T,  256, 256);
    kLN<<<65536, 256, 0, stream>>>(inputs, gin, bin, xlnw);
    for (int it = 0; it < 3; ++it) {
        kB1<<<64, 256, 0, stream>>>(slots, gs, bs, WqT, bq, Wk, bk, q2w, cw);
        kB2<<<dim3(64, 64), 256, 0, stream>>>(q2w, cw, xlnw, attn_out, partw, aspw, it == 2);
        kB2r<<<512, 256, 0, stream>>>(partw, aspw, u2g, asumg);
        kB3<<<128, 256, 0, stream>>>(u2g, asumg, slots, WvT, bv, WihT, bih, WhhT, bhh,
                                     W1T, b1, W2T, b2, gf, bff,
                                     (it == 2) ? out : slots);
    }
}